// Round 9
// baseline (1702.547 us; speedup 1.0000x reference)
//
#include <hip/hip_runtime.h>
#include <math.h>

// TrfEdgeNetRand: 3x TransformerConv(heads=1) + ReLU + classifier on MI355X.
// R15: R12 base (986us, best passing) + degree-sorted node permutation.
//  - R14 post-mortem: batch-8 spilled (WRITE 50->125MB, FETCH +39MB; 8xuint4
//    arrays > (256,6) ~80-VGPR cap). R13: more waves thrashed L2. Both edge2
//    levers falsified -> batch-4 @ (256,6) is the per-wave sweet spot.
//  - Remaining waste: degree divergence. Node-per-group with 2 (C=256) or 4
//    (C=128) groups/wave; degrees ~Poisson(8) -> wave runs max(d_g):
//    E[max2]=+22%, E[max4]=+44% idle issue slots. Fix: 64-bucket counting
//    sort of nodes by degree (3 tiny kernels, ~10us once); perm[] makes
//    co-resident groups near-equal trip count. Gathers/numerics unchanged.
//  - k_edge2 reverted to R12's exact batch-4 body (+perm indexing).

typedef unsigned int uint;
typedef unsigned short ushort;
typedef _Float16 f16x8 __attribute__((ext_vector_type(8)));
typedef _Float16 h16x2 __attribute__((ext_vector_type(2)));
typedef float f32x4 __attribute__((ext_vector_type(4)));
typedef float f32x2 __attribute__((ext_vector_type(2)));

__device__ __forceinline__ ushort f2h(float f) {
    return __builtin_bit_cast(ushort, (_Float16)f);   // v_cvt_f16_f32 (RNE)
}
__device__ __forceinline__ float h2f(ushort h) {
    return (float)__builtin_bit_cast(_Float16, h);
}
__device__ __forceinline__ h16x2 bch2(uint u) { return __builtin_bit_cast(h16x2, u); }
__device__ __forceinline__ f32x2 cvt2(uint u) {
    h16x2 h = bch2(u);
    return (f32x2){(float)h.x, (float)h.y};
}

#if __has_builtin(__builtin_amdgcn_fdot2)
#define FDOT2(a, b, c) __builtin_amdgcn_fdot2((a), (b), (c), false)
#else
__device__ __forceinline__ float fdot2_sw(h16x2 a, h16x2 b, float c) {
    return fmaf((float)a.x, (float)b.x, fmaf((float)a.y, (float)b.y, c));
}
#define FDOT2(a, b, c) fdot2_sw((a), (b), (c))
#endif

// ---------------- utility kernels ----------------
__global__ void k_zero(uint* p, int n) {
    int i = blockIdx.x * 256 + threadIdx.x;
    if (i < n) p[i] = 0u;
}

__global__ void k_hist(const int* __restrict__ dst, uint* __restrict__ counts, int E, int N) {
    int e = blockIdx.x * 256 + threadIdx.x;
    if (e < E) {
        int d = dst[e];
        d = (d < 0) ? 0 : (d >= N ? N - 1 : d);
        atomicAdd(&counts[d], 1u);
    }
}

__global__ void k_scan1(const uint* __restrict__ counts, uint* __restrict__ bsum, int n) {
    __shared__ uint sm[256];
    int tid = threadIdx.x;
    int base = blockIdx.x * 1024 + tid * 4;
    uint s = 0;
#pragma unroll
    for (int j = 0; j < 4; ++j)
        if (base + j < n) s += counts[base + j];
    sm[tid] = s;
    __syncthreads();
    for (int d = 128; d > 0; d >>= 1) {
        if (tid < d) sm[tid] += sm[tid + d];
        __syncthreads();
    }
    if (tid == 0) bsum[blockIdx.x] = sm[0];
}

__global__ void k_scan2(uint* bsum, int nb) {
    if (threadIdx.x == 0 && blockIdx.x == 0) {
        uint run = 0;
        for (int i = 0; i < nb; ++i) { uint v = bsum[i]; bsum[i] = run; run += v; }
    }
}

__global__ void k_scan3(const uint* __restrict__ counts, const uint* __restrict__ bsum,
                        uint* __restrict__ row_ptr, int n, int E) {
    __shared__ uint sm[256];
    int tid = threadIdx.x;
    int base = blockIdx.x * 1024 + tid * 4;
    uint local[4];
    uint s = 0;
#pragma unroll
    for (int j = 0; j < 4; ++j) {
        local[j] = (base + j < n) ? counts[base + j] : 0u;
        s += local[j];
    }
    sm[tid] = s;
    __syncthreads();
    for (int d = 1; d < 256; d <<= 1) {
        uint v = (tid >= d) ? sm[tid - d] : 0u;
        __syncthreads();
        sm[tid] += v;
        __syncthreads();
    }
    uint run = sm[tid] - s + bsum[blockIdx.x];
#pragma unroll
    for (int j = 0; j < 4; ++j)
        if (base + j < n) { row_ptr[base + j] = run; run += local[j]; }
    if (blockIdx.x == 0 && tid == 0) row_ptr[n] = (uint)E;
}

__global__ void k_fill(const int* __restrict__ ei, const uint* __restrict__ row_ptr,
                       uint* __restrict__ cursor, int2* __restrict__ srcid, int E, int N) {
    int e = blockIdx.x * 256 + threadIdx.x;
    if (e >= E) return;
    int s = ei[e];
    int d = ei[E + e];
    s = (s < 0) ? 0 : (s >= N ? N - 1 : s);
    d = (d < 0) ? 0 : (d >= N ? N - 1 : d);
    uint idx = row_ptr[d] + atomicAdd(&cursor[d], 1u);
    srcid[idx] = make_int2(s, e);
}

// ---- degree counting sort: perm[slot] = node, ascending degree ----
__global__ void k_dhist(const uint* __restrict__ row_ptr, uint* __restrict__ dcnt, int N) {
    int i = blockIdx.x * 256 + threadIdx.x;
    if (i < N) {
        uint d = row_ptr[i + 1] - row_ptr[i];
        if (d > 63u) d = 63u;
        atomicAdd(&dcnt[d], 1u);
    }
}

__global__ void k_dscan(uint* dcnt) {    // in-place exclusive scan, 64 entries
    if (threadIdx.x == 0 && blockIdx.x == 0) {
        uint run = 0;
        for (int i = 0; i < 64; ++i) { uint v = dcnt[i]; dcnt[i] = run; run += v; }
    }
}

__global__ void k_dfill(const uint* __restrict__ row_ptr, uint* __restrict__ dcur,
                        uint* __restrict__ perm, int N) {
    int i = blockIdx.x * 256 + threadIdx.x;
    if (i < N) {
        uint d = row_ptr[i + 1] - row_ptr[i];
        if (d > 63u) d = 63u;
        uint idx = atomicAdd(&dcur[d], 1u);
        perm[idx] = (uint)i;
    }
}

__global__ void k_cvt(const float4* __restrict__ in, ushort4* __restrict__ outp, int n4) {
    int i = blockIdx.x * 256 + threadIdx.x;
    if (i >= n4) return;
    float4 v = in[i];
    ushort4 o;
    o.x = f2h(v.x); o.y = f2h(v.y); o.z = f2h(v.z); o.w = f2h(v.w);
    outp[i] = o;
}

// ---------------- g-projection pre-pack: Wgf[k][f] = sum_c Wq[k,c]*We[f,c] ----
__global__ void k_packg(const float* __restrict__ Wq, const float* __restrict__ bq,
                        const float* __restrict__ We, float* __restrict__ Wgf,
                        float* __restrict__ bgf, int C) {
    int id = blockIdx.x * 256 + threadIdx.x;
    if (id < 2048) {
        int k = id >> 4, f = id & 15;
        float s = 0.f;
        for (int c = 0; c < C; ++c) s = fmaf(Wq[k * C + c], We[f * C + c], s);
        Wgf[id] = s;              // layout [k*16+f]
    } else if (id < 2064) {
        int f = id - 2048;
        float s = 0.f;
        for (int c = 0; c < C; ++c) s = fmaf(bq[c], We[f * C + c], s);
        bgf[f] = s;
    }
}

// ---------------- weight packing (cols: Wq|Wk|Wv|Ws|Wg -> 4C+16) -------------
__global__ void k_packw(const float* __restrict__ Wq, const float* __restrict__ Wk,
                        const float* __restrict__ Wv, const float* __restrict__ Ws,
                        const float* __restrict__ Wgf, ushort* __restrict__ Bp, int C) {
    int nct = (4 * C + 16) >> 4;
    int total = 4 * nct * 512;
    int id = blockIdx.x * 256 + threadIdx.x;
    if (id >= total) return;
    int j = id & 7;
    int rest = id >> 3;
    int lane = rest & 63;
    rest >>= 6;
    int ct = rest % nct;
    int kt = rest / nct;
    int k = kt * 32 + ((lane >> 4) << 3) + j;
    int c = (ct << 4) + (lane & 15);
    float w;
    if (c < 4 * C) {
        int mat = c / C, cc = c % C;
        const float* W = (mat == 0) ? Wq : (mat == 1) ? Wk : (mat == 2) ? Wv : Ws;
        w = W[k * C + cc];
    } else {
        w = Wgf[k * 16 + (c - 4 * C)];
    }
    Bp[id] = f2h(w);
}

__global__ void k_bias(const float* __restrict__ bq, const float* __restrict__ bk,
                       const float* __restrict__ bv, const float* __restrict__ bs,
                       const float* __restrict__ bgf, float* __restrict__ outp, int C) {
    int c = blockIdx.x * 256 + threadIdx.x;
    if (c >= 4 * C + 16) return;
    float v;
    if (c < 4 * C) {
        int mat = c / C, cc = c % C;
        const float* b = (mat == 0) ? bq : (mat == 1) ? bk : (mat == 2) ? bv : bs;
        v = b[cc];
    } else {
        v = bgf[c - 4 * C];
    }
    outp[c] = v;
}

// ---------------- fused QKVSG GEMM (f16 MFMA), B-resident row-tile loop ------
// A: [N,128] f16. Cols [0,3C)->H (q|k|v), [3C,4C)->S (skip), [4C,4C+16)->g.
__global__ __launch_bounds__(256, 4) void k_gemm(const ushort* __restrict__ A,
                                                 const ushort* __restrict__ Bp,
                                                 const float* __restrict__ bias,
                                                 ushort* __restrict__ H,
                                                 ushort* __restrict__ S,
                                                 ushort* __restrict__ g,
                                                 int C, int mt_total) {
    constexpr int RT = 8;
    int fourC = 4 * C, threeC = 3 * C;
    int P = fourC + 16;
    int nct = P >> 4;
    int lane = threadIdx.x & 63;
    int wave = threadIdx.x >> 6;
    int quad = lane >> 4;
    int r = lane & 15;
    int c0 = (blockIdx.x << 8) + (wave << 6);
    int ct0 = c0 >> 4;
    if (ct0 >= nct) return;

    // B fragments: loaded once, register-resident across all row-tiles
    f16x8 bf[16];
#pragma unroll
    for (int kk = 0; kk < 4; ++kk)
#pragma unroll
        for (int i = 0; i < 4; ++i) {
            if (ct0 + i < nct)
                bf[kk * 4 + i] = *(const f16x8*)(Bp + ((size_t)((kk * nct + ct0 + i) << 6) + lane) * 8);
            else
                bf[kk * 4 + i] = __builtin_bit_cast(f16x8, (uint4){0u, 0u, 0u, 0u});
        }

    float bi4[4];
#pragma unroll
    for (int i = 0; i < 4; ++i) {
        int cc = c0 + (i << 4) + r;
        bi4[i] = (cc < P) ? bias[cc] : 0.f;
    }

    int mt0 = blockIdx.y * RT;
    int mt_end = mt0 + RT;
    if (mt_end > mt_total) mt_end = mt_total;

    for (int mt = mt0; mt < mt_end; ++mt) {
        int m0 = mt << 4;
        const ushort* arow = A + (size_t)(m0 + r) * 128 + (quad << 3);

        f32x4 acc[4];
#pragma unroll
        for (int i = 0; i < 4; ++i) acc[i] = (f32x4){0.f, 0.f, 0.f, 0.f};

#pragma unroll
        for (int kk = 0; kk < 4; ++kk) {
            f16x8 a = *(const f16x8*)(arow + kk * 32);
#pragma unroll
            for (int i = 0; i < 4; ++i)
                if (ct0 + i < nct)
                    acc[i] = __builtin_amdgcn_mfma_f32_16x16x32_f16(a, bf[kk * 4 + i], acc[i], 0, 0, 0);
        }

        // R9-proven scatter epilogue (C-layout: col=c0+i*16+r, row=quad*4+reg)
#pragma unroll
        for (int i = 0; i < 4; ++i) {
            int cc = c0 + (i << 4) + r;
            if (cc >= P) continue;
#pragma unroll
            for (int reg = 0; reg < 4; ++reg) {
                int rr = m0 + (quad << 2) + reg;
                ushort val = f2h(acc[i][reg] + bi4[i]);
                if (cc < threeC)      H[(size_t)rr * threeC + cc] = val;
                else if (cc < fourC)  S[(size_t)rr * C + (cc - threeC)] = val;
                else                  g[(size_t)rr * 16 + (cc - fourC)] = val;
            }
        }
    }
}

// ---------------- edge pass 1: logits -> e (per edge), w,l (per node) --------
// Gathers K + eattr only. g buffer is read early (g = We^T q) and overwritten
// late with w = sum e*attr (f16) -- same group, same row, read-before-write.
// node = perm[slot]: degree-sorted so co-resident groups have equal trip count.
template <int C, int GSIZE>
__global__ __launch_bounds__(256, 6) void k_edge1(const ushort* __restrict__ H,
                                                  ushort* g,   // in: g, out: w
                                                  const uint* __restrict__ row_ptr,
                                                  const int2* __restrict__ srcid,
                                                  const float* __restrict__ eattr,
                                                  const uint* __restrict__ perm,
                                                  ushort* __restrict__ ebuf,
                                                  float* __restrict__ lbuf, int N) {
    constexpr int VR = C / GSIZE;        // 8
    constexpr int TH = 3 * C;
    constexpr int GPB = 256 / GSIZE;
    const float scale = (C == 128) ? 0.08838834764831843f : 0.0625f;  // 1/sqrt(C)
    const float foldk = 16.0f / (float)GSIZE;  // attr replication compensation

    int lane = threadIdx.x & (GSIZE - 1);
    int grp = threadIdx.x / GSIZE;
    int f = lane & 15;
    int slot = blockIdx.x * GPB + grp;
    if (slot >= N) return;
    int node = (int)perm[slot];
    int lvr = lane * VR;

    uint4 qv = *(const uint4*)(H + (size_t)node * TH + lvr);
    h16x2 q0 = bch2(qv.x), q1 = bch2(qv.y), q2 = bch2(qv.z), q3 = bch2(qv.w);
    float fg = foldk * h2f(g[(size_t)node * 16 + f]);
    uint beg = row_ptr[node], end = row_ptr[node + 1];

    float l = 0.f, w = 0.f;
    for (uint t = beg; t < end; t += 4) {
        uint t1 = (t + 1 < end) ? t + 1 : t;   // replicate-last; masked by e=0
        uint t2 = (t + 2 < end) ? t + 2 : t;
        uint t3 = (t + 3 < end) ? t + 3 : t;
        int2 se0 = srcid[t], se1 = srcid[t1], se2 = srcid[t2], se3 = srcid[t3];
        float at0 = eattr[(size_t)se0.y * 16 + f];
        float at1 = eattr[(size_t)se1.y * 16 + f];
        float at2 = eattr[(size_t)se2.y * 16 + f];
        float at3 = eattr[(size_t)se3.y * 16 + f];
        uint4 k0 = *(const uint4*)(H + (size_t)se0.x * TH + C + lvr);
        uint4 k1 = *(const uint4*)(H + (size_t)se1.x * TH + C + lvr);
        uint4 k2 = *(const uint4*)(H + (size_t)se2.x * TH + C + lvr);
        uint4 k3 = *(const uint4*)(H + (size_t)se3.x * TH + C + lvr);

        float p0 = at0 * fg, p1 = at1 * fg, p2 = at2 * fg, p3 = at3 * fg;
        p0 = FDOT2(q0, bch2(k0.x), p0); p0 = FDOT2(q1, bch2(k0.y), p0);
        p0 = FDOT2(q2, bch2(k0.z), p0); p0 = FDOT2(q3, bch2(k0.w), p0);
        p1 = FDOT2(q0, bch2(k1.x), p1); p1 = FDOT2(q1, bch2(k1.y), p1);
        p1 = FDOT2(q2, bch2(k1.z), p1); p1 = FDOT2(q3, bch2(k1.w), p1);
        p2 = FDOT2(q0, bch2(k2.x), p2); p2 = FDOT2(q1, bch2(k2.y), p2);
        p2 = FDOT2(q2, bch2(k2.z), p2); p2 = FDOT2(q3, bch2(k2.w), p2);
        p3 = FDOT2(q0, bch2(k3.x), p3); p3 = FDOT2(q1, bch2(k3.y), p3);
        p3 = FDOT2(q2, bch2(k3.z), p3); p3 = FDOT2(q3, bch2(k3.w), p3);

        p0 += __shfl_xor(p0, 1); p1 += __shfl_xor(p1, 1);
        p2 += __shfl_xor(p2, 1); p3 += __shfl_xor(p3, 1);
        p0 += __shfl_xor(p0, 2); p1 += __shfl_xor(p1, 2);
        p2 += __shfl_xor(p2, 2); p3 += __shfl_xor(p3, 2);
        p0 += __shfl_xor(p0, 4); p1 += __shfl_xor(p1, 4);
        p2 += __shfl_xor(p2, 4); p3 += __shfl_xor(p3, 4);
        p0 += __shfl_xor(p0, 8); p1 += __shfl_xor(p1, 8);
        p2 += __shfl_xor(p2, 8); p3 += __shfl_xor(p3, 8);
        if (GSIZE == 32) {
            p0 += __shfl_xor(p0, 16); p1 += __shfl_xor(p1, 16);
            p2 += __shfl_xor(p2, 16); p3 += __shfl_xor(p3, 16);
        }
        float e0 = __expf(p0 * scale);
        float e1 = (t + 1 < end) ? __expf(p1 * scale) : 0.f;
        float e2 = (t + 2 < end) ? __expf(p2 * scale) : 0.f;
        float e3 = (t + 3 < end) ? __expf(p3 * scale) : 0.f;
        l += (e0 + e1) + (e2 + e3);
        w = fmaf(e0, at0, w); w = fmaf(e1, at1, w);
        w = fmaf(e2, at2, w); w = fmaf(e3, at3, w);
        if (lane < 4) {                      // lanes 0..3 store valid slots only
            uint tj = t + lane;
            if (tj < end) {
                float ee = (lane == 0) ? e0 : (lane == 1) ? e1 : (lane == 2) ? e2 : e3;
                ebuf[tj] = f2h(ee);
            }
        }
    }
    if (lane < 16) g[(size_t)node * 16 + lane] = f2h(w);  // overwrite g with w
    if (lane == 0) lbuf[node] = l;
}

// ---------------- edge pass 2: out = (sum e*v + w.We)/l + skip ---------------
// Gathers V only; batch-4 (R12-proven). node = perm[slot].
template <int C, int GSIZE, bool RELU>
__global__ __launch_bounds__(256, 6) void k_edge2(const ushort* __restrict__ H,
                                                  ushort* __restrict__ S,
                                                  const uint* __restrict__ row_ptr,
                                                  const int2* __restrict__ srcid,
                                                  const ushort* __restrict__ ebuf,
                                                  const ushort* __restrict__ wbuf,
                                                  const float* __restrict__ lbuf,
                                                  const uint* __restrict__ perm,
                                                  const float* __restrict__ We, int N) {
    constexpr int VR = C / GSIZE;        // 8
    constexpr int TH = 3 * C;
    constexpr int GPB = 256 / GSIZE;
    __shared__ float swex[GPB][17];      // +1 pad: conflict-free group reads

    int lane = threadIdx.x & (GSIZE - 1);
    int grp = threadIdx.x / GSIZE;
    int slot = blockIdx.x * GPB + grp;
    if (slot >= N) return;
    int node = (int)perm[slot];
    int lvr = lane * VR;
    uint beg = row_ptr[node], end = row_ptr[node + 1];

    ushort* srow = S + (size_t)node * C + lvr;
    uint4 skv = *(const uint4*)srow;                     // early skip load
    if (lane < 16) swex[grp][lane] = h2f(wbuf[(size_t)node * 16 + lane]);
    float l = lbuf[node];

    f32x2 acc[4];
#pragma unroll
    for (int j = 0; j < 4; ++j) acc[j] = (f32x2){0.f, 0.f};

    for (uint t = beg; t < end; t += 4) {
        uint t1 = (t + 1 < end) ? t + 1 : t;
        uint t2 = (t + 2 < end) ? t + 2 : t;
        uint t3 = (t + 3 < end) ? t + 3 : t;
        int s0 = srcid[t].x, s1 = srcid[t1].x, s2 = srcid[t2].x, s3 = srcid[t3].x;
        float e0 = h2f(ebuf[t]);
        float e1 = (t + 1 < end) ? h2f(ebuf[t1]) : 0.f;
        float e2 = (t + 2 < end) ? h2f(ebuf[t2]) : 0.f;
        float e3 = (t + 3 < end) ? h2f(ebuf[t3]) : 0.f;
        uint4 v0 = *(const uint4*)(H + (size_t)s0 * TH + 2 * C + lvr);
        uint4 v1 = *(const uint4*)(H + (size_t)s1 * TH + 2 * C + lvr);
        uint4 v2 = *(const uint4*)(H + (size_t)s2 * TH + 2 * C + lvr);
        uint4 v3 = *(const uint4*)(H + (size_t)s3 * TH + 2 * C + lvr);
        f32x2 eb;
        eb = (f32x2){e0, e0};
        acc[0] = __builtin_elementwise_fma(cvt2(v0.x), eb, acc[0]);
        acc[1] = __builtin_elementwise_fma(cvt2(v0.y), eb, acc[1]);
        acc[2] = __builtin_elementwise_fma(cvt2(v0.z), eb, acc[2]);
        acc[3] = __builtin_elementwise_fma(cvt2(v0.w), eb, acc[3]);
        eb = (f32x2){e1, e1};
        acc[0] = __builtin_elementwise_fma(cvt2(v1.x), eb, acc[0]);
        acc[1] = __builtin_elementwise_fma(cvt2(v1.y), eb, acc[1]);
        acc[2] = __builtin_elementwise_fma(cvt2(v1.z), eb, acc[2]);
        acc[3] = __builtin_elementwise_fma(cvt2(v1.w), eb, acc[3]);
        eb = (f32x2){e2, e2};
        acc[0] = __builtin_elementwise_fma(cvt2(v2.x), eb, acc[0]);
        acc[1] = __builtin_elementwise_fma(cvt2(v2.y), eb, acc[1]);
        acc[2] = __builtin_elementwise_fma(cvt2(v2.z), eb, acc[2]);
        acc[3] = __builtin_elementwise_fma(cvt2(v2.w), eb, acc[3]);
        eb = (f32x2){e3, e3};
        acc[0] = __builtin_elementwise_fma(cvt2(v3.x), eb, acc[0]);
        acc[1] = __builtin_elementwise_fma(cvt2(v3.y), eb, acc[1]);
        acc[2] = __builtin_elementwise_fma(cvt2(v3.z), eb, acc[2]);
        acc[3] = __builtin_elementwise_fma(cvt2(v3.w), eb, acc[3]);
    }

    float inv = 1.f / (l + 1e-16f);   // empty node: acc=w=0 -> out = skip
    f32x2 ew[4];
#pragma unroll
    for (int j = 0; j < 4; ++j) ew[j] = (f32x2){0.f, 0.f};
#pragma unroll
    for (int f2i = 0; f2i < 16; ++f2i) {
        float wfs = swex[grp][f2i];
        f32x2 wf = (f32x2){wfs, wfs};
        const f32x4* wrow = (const f32x4*)(We + f2i * C + lvr);
        f32x4 c0 = wrow[0], c1 = wrow[1];
        ew[0] = __builtin_elementwise_fma(c0.lo, wf, ew[0]);
        ew[1] = __builtin_elementwise_fma(c0.hi, wf, ew[1]);
        ew[2] = __builtin_elementwise_fma(c1.lo, wf, ew[2]);
        ew[3] = __builtin_elementwise_fma(c1.hi, wf, ew[3]);
    }
    const uint* sp = (const uint*)&skv;
    uint4 ov;
    uint* op = (uint*)&ov;
#pragma unroll
    for (int hh = 0; hh < 4; ++hh) {
        f32x2 sk = cvt2(sp[hh]);
        float o0 = (acc[hh].x + ew[hh].x) * inv + sk.x;
        float o1 = (acc[hh].y + ew[hh].y) * inv + sk.y;
        if (RELU) { o0 = fmaxf(o0, 0.f); o1 = fmaxf(o1, 0.f); }
        op[hh] = (uint)f2h(o0) | ((uint)f2h(o1) << 16);
    }
    *(uint4*)srow = ov;
}

// ---------------- classifier: out[N,10] = h3(f16) @ Wc + bc ----------------
__global__ void k_cls(const ushort* __restrict__ h, const float* __restrict__ Wc,
                      const float* __restrict__ bc, float* __restrict__ outp, int N) {
    int t = blockIdx.x * 256 + threadIdx.x;
    int node = t >> 4;
    int c = t & 15;
    if (node >= N || c >= 10) return;
    const ushort* hr = h + (size_t)node * 256;
    float acc = 0.f;
#pragma unroll 4
    for (int k4 = 0; k4 < 64; ++k4) {
        uint2 u = *(const uint2*)(hr + k4 * 4);
        f32x2 a01 = cvt2(u.x);
        f32x2 a23 = cvt2(u.y);
        int kb = k4 * 4;
        acc = fmaf(a01.x, Wc[(kb + 0) * 10 + c], acc);
        acc = fmaf(a01.y, Wc[(kb + 1) * 10 + c], acc);
        acc = fmaf(a23.x, Wc[(kb + 2) * 10 + c], acc);
        acc = fmaf(a23.y, Wc[(kb + 3) * 10 + c], acc);
    }
    outp[node * 10 + c] = acc + bc[c];
}

// ---------------- launch ----------------
extern "C" void kernel_launch(void* const* d_in, const int* in_sizes, int n_in,
                              void* d_out, int out_size, void* d_ws, size_t ws_size,
                              hipStream_t stream) {
    const float* x = (const float*)d_in[0];
    const int* ei = (const int*)d_in[1];
    const float* eattr = (const float*)d_in[2];
    const int N = in_sizes[0] / 128;
    const int E = in_sizes[1] / 2;

    const float* Wq[3], *bq[3], *Wk[3], *bk[3], *Wv[3], *bv[3], *We[3], *Ws[3], *bs[3];
    for (int li = 0; li < 3; ++li) {
        int base = 3 + li * 9;
        Wq[li] = (const float*)d_in[base + 0];
        bq[li] = (const float*)d_in[base + 1];
        Wk[li] = (const float*)d_in[base + 2];
        bk[li] = (const float*)d_in[base + 3];
        Wv[li] = (const float*)d_in[base + 4];
        bv[li] = (const float*)d_in[base + 5];
        We[li] = (const float*)d_in[base + 6];
        Ws[li] = (const float*)d_in[base + 7];
        bs[li] = (const float*)d_in[base + 8];
    }
    const float* Wc = (const float*)d_in[30];
    const float* bc = (const float*)d_in[31];

    // workspace carve (~244 MB -- R12 budget + perm 0.4MB + dcnt)
    size_t off = 0;
    char* base = (char*)d_ws;
    auto alloc = [&](size_t bytes) -> void* {
        void* p = base + off;
        off = (off + bytes + 255) & ~(size_t)255;
        return p;
    };
    ushort* SA = (ushort*)alloc((size_t)N * 256 * 2);   // skip/out ping
    ushort* SB = (ushort*)alloc((size_t)N * 128 * 2);   // pong (also xb)
    ushort* H  = (ushort*)alloc((size_t)N * 768 * 2);   // q|k|v (max 3C)
    ushort* gbuf = (ushort*)alloc((size_t)N * 16 * 2);  // g = We.q; then w
    ushort* Bp = (ushort*)alloc(140000 * 2);            // packed weights
    float* biasc = (float*)alloc(1040 * 4);
    float* Wgf = (float*)alloc(2048 * 4);
    float* bgf = (float*)alloc(16 * 4);
    uint* row_ptr = (uint*)alloc((size_t)(N + 1) * 4);
    uint* counts = (uint*)alloc((size_t)N * 4);
    uint* cursor = (uint*)alloc((size_t)N * 4);
    uint* bsum = (uint*)alloc(1024 * 4);
    int2* srcid = (int2*)alloc((size_t)E * 8);          // CSR {src, eidx}
    ushort* ebuf = (ushort*)alloc((size_t)E * 2);       // pass1 -> pass2 e (f16)
    uint* perm = (uint*)alloc((size_t)N * 4);           // degree-sorted nodes
    uint* dcnt = (uint*)alloc(64 * 4);                  // degree buckets

    ushort* xb = SB;             // alias: xb dead after layer-1 GEMM
    float* lbuf = (float*)counts; // alias: counts dead after CSR build

    int nb = (N + 1023) / 1024;

    // CSR build
    k_zero<<<(N + 255) / 256, 256, 0, stream>>>(counts, N);
    k_zero<<<(N + 255) / 256, 256, 0, stream>>>(cursor, N);
    k_hist<<<(E + 255) / 256, 256, 0, stream>>>(ei + E, counts, E, N);
    k_scan1<<<nb, 256, 0, stream>>>(counts, bsum, N);
    k_scan2<<<1, 64, 0, stream>>>(bsum, nb);
    k_scan3<<<nb, 256, 0, stream>>>(counts, bsum, row_ptr, N, E);
    k_fill<<<(E + 255) / 256, 256, 0, stream>>>(ei, row_ptr, cursor, srcid, E, N);

    // degree counting sort -> perm (equal trip counts per wave)
    k_zero<<<1, 64, 0, stream>>>(dcnt, 64);
    k_dhist<<<(N + 255) / 256, 256, 0, stream>>>(row_ptr, dcnt, N);
    k_dscan<<<1, 64, 0, stream>>>(dcnt);
    k_dfill<<<(N + 255) / 256, 256, 0, stream>>>(row_ptr, dcnt, perm, N);

    // x -> f16
    int n4 = N * 128 / 4;
    k_cvt<<<(n4 + 255) / 256, 256, 0, stream>>>((const float4*)x, (ushort4*)xb, n4);

    int mt_total = N / 16;    // N divisible by 16
    for (int li = 0; li < 3; ++li) {
        int C = (li == 2) ? 256 : 128;
        int P = 4 * C + 16;
        int packTotal = 4 * (P >> 4) * 512;
        const ushort* A = (li == 0) ? xb : (li == 1) ? SA : SB;
        ushort* Sout = (li == 1) ? SB : SA;

        k_packg<<<9, 256, 0, stream>>>(Wq[li], bq[li], We[li], Wgf, bgf, C);
        k_packw<<<(packTotal + 255) / 256, 256, 0, stream>>>(Wq[li], Wk[li], Wv[li], Ws[li], Wgf, Bp, C);
        k_bias<<<(P + 255) / 256, 256, 0, stream>>>(bq[li], bk[li], bv[li], bs[li], bgf, biasc, C);
        k_gemm<<<dim3((P + 255) / 256, (mt_total + 7) / 8), 256, 0, stream>>>(A, Bp, biasc, H, Sout, gbuf, C, mt_total);
        if (li == 2) {
            k_edge1<256, 32><<<(N * 32 + 255) / 256, 256, 0, stream>>>(H, gbuf, row_ptr, srcid, eattr, perm, ebuf, lbuf, N);
            k_edge2<256, 32, false><<<(N * 32 + 255) / 256, 256, 0, stream>>>(H, Sout, row_ptr, srcid, ebuf, gbuf, lbuf, perm, We[li], N);
        } else {
            k_edge1<128, 16><<<(N * 16 + 255) / 256, 256, 0, stream>>>(H, gbuf, row_ptr, srcid, eattr, perm, ebuf, lbuf, N);
            k_edge2<128, 16, true><<<(N * 16 + 255) / 256, 256, 0, stream>>>(H, Sout, row_ptr, srcid, ebuf, gbuf, lbuf, perm, We[li], N);
        }
    }

    // classifier (layer-3 output is in SA)
    k_cls<<<(N * 16 + 255) / 256, 256, 0, stream>>>(SA, Wc, bc, (float*)d_out, N);
}

// Round 10
// 1016.127 us; speedup vs baseline: 1.6755x; 1.6755x over previous
//
#include <hip/hip_runtime.h>
#include <math.h>

// TrfEdgeNetRand: 3x TransformerConv(heads=1) + ReLU + classifier on MI355X.
// R16: R15's degree-sorted perm with a contention-free counting sort.
//  - R15 post-mortem: 1702us regression was ENTIRELY the sort kernels --
//    k_dhist/k_dfill did 100K global atomicAdds onto 64 addresses (modal
//    bucket ~14K serialized RMWs -> 341us each, VALUBusy 0.007%). The perm
//    itself passed correctness; divergence benefit still unmeasured.
//  - Fix: two-level histogram. Per-block LDS hist (LDS atomics), then 64
//    global atomics/block (spread over 64 addresses). k_dfill claims a base
//    range per bucket per block, ranks within block via LDS, writes perm.
//    Global atomics 100K -> 25K spread; expected ~10-25us combined.
//  - Edge kernels, gemm, carve: byte-identical to R15 (R12 + perm indexing).

typedef unsigned int uint;
typedef unsigned short ushort;
typedef _Float16 f16x8 __attribute__((ext_vector_type(8)));
typedef _Float16 h16x2 __attribute__((ext_vector_type(2)));
typedef float f32x4 __attribute__((ext_vector_type(4)));
typedef float f32x2 __attribute__((ext_vector_type(2)));

__device__ __forceinline__ ushort f2h(float f) {
    return __builtin_bit_cast(ushort, (_Float16)f);   // v_cvt_f16_f32 (RNE)
}
__device__ __forceinline__ float h2f(ushort h) {
    return (float)__builtin_bit_cast(_Float16, h);
}
__device__ __forceinline__ h16x2 bch2(uint u) { return __builtin_bit_cast(h16x2, u); }
__device__ __forceinline__ f32x2 cvt2(uint u) {
    h16x2 h = bch2(u);
    return (f32x2){(float)h.x, (float)h.y};
}

#if __has_builtin(__builtin_amdgcn_fdot2)
#define FDOT2(a, b, c) __builtin_amdgcn_fdot2((a), (b), (c), false)
#else
__device__ __forceinline__ float fdot2_sw(h16x2 a, h16x2 b, float c) {
    return fmaf((float)a.x, (float)b.x, fmaf((float)a.y, (float)b.y, c));
}
#define FDOT2(a, b, c) fdot2_sw((a), (b), (c))
#endif

// ---------------- utility kernels ----------------
__global__ void k_zero(uint* p, int n) {
    int i = blockIdx.x * 256 + threadIdx.x;
    if (i < n) p[i] = 0u;
}

__global__ void k_hist(const int* __restrict__ dst, uint* __restrict__ counts, int E, int N) {
    int e = blockIdx.x * 256 + threadIdx.x;
    if (e < E) {
        int d = dst[e];
        d = (d < 0) ? 0 : (d >= N ? N - 1 : d);
        atomicAdd(&counts[d], 1u);
    }
}

__global__ void k_scan1(const uint* __restrict__ counts, uint* __restrict__ bsum, int n) {
    __shared__ uint sm[256];
    int tid = threadIdx.x;
    int base = blockIdx.x * 1024 + tid * 4;
    uint s = 0;
#pragma unroll
    for (int j = 0; j < 4; ++j)
        if (base + j < n) s += counts[base + j];
    sm[tid] = s;
    __syncthreads();
    for (int d = 128; d > 0; d >>= 1) {
        if (tid < d) sm[tid] += sm[tid + d];
        __syncthreads();
    }
    if (tid == 0) bsum[blockIdx.x] = sm[0];
}

__global__ void k_scan2(uint* bsum, int nb) {
    if (threadIdx.x == 0 && blockIdx.x == 0) {
        uint run = 0;
        for (int i = 0; i < nb; ++i) { uint v = bsum[i]; bsum[i] = run; run += v; }
    }
}

__global__ void k_scan3(const uint* __restrict__ counts, const uint* __restrict__ bsum,
                        uint* __restrict__ row_ptr, int n, int E) {
    __shared__ uint sm[256];
    int tid = threadIdx.x;
    int base = blockIdx.x * 1024 + tid * 4;
    uint local[4];
    uint s = 0;
#pragma unroll
    for (int j = 0; j < 4; ++j) {
        local[j] = (base + j < n) ? counts[base + j] : 0u;
        s += local[j];
    }
    sm[tid] = s;
    __syncthreads();
    for (int d = 1; d < 256; d <<= 1) {
        uint v = (tid >= d) ? sm[tid - d] : 0u;
        __syncthreads();
        sm[tid] += v;
        __syncthreads();
    }
    uint run = sm[tid] - s + bsum[blockIdx.x];
#pragma unroll
    for (int j = 0; j < 4; ++j)
        if (base + j < n) { row_ptr[base + j] = run; run += local[j]; }
    if (blockIdx.x == 0 && tid == 0) row_ptr[n] = (uint)E;
}

__global__ void k_fill(const int* __restrict__ ei, const uint* __restrict__ row_ptr,
                       uint* __restrict__ cursor, int2* __restrict__ srcid, int E, int N) {
    int e = blockIdx.x * 256 + threadIdx.x;
    if (e >= E) return;
    int s = ei[e];
    int d = ei[E + e];
    s = (s < 0) ? 0 : (s >= N ? N - 1 : s);
    d = (d < 0) ? 0 : (d >= N ? N - 1 : d);
    uint idx = row_ptr[d] + atomicAdd(&cursor[d], 1u);
    srcid[idx] = make_int2(s, e);
}

// ---- degree counting sort (two-level, contention-free) ----
__global__ void k_dhist(const uint* __restrict__ row_ptr, uint* __restrict__ dcnt, int N) {
    __shared__ uint lh[64];
    int tid = threadIdx.x;
    if (tid < 64) lh[tid] = 0u;
    __syncthreads();
    int i = blockIdx.x * 256 + tid;
    if (i < N) {
        uint d = row_ptr[i + 1] - row_ptr[i];
        if (d > 63u) d = 63u;
        atomicAdd(&lh[d], 1u);          // LDS atomic: cheap
    }
    __syncthreads();
    if (tid < 64 && lh[tid]) atomicAdd(&dcnt[tid], lh[tid]);  // 64/block, spread
}

__global__ void k_dscan(uint* dcnt) {    // in-place exclusive scan, 64 entries
    if (threadIdx.x == 0 && blockIdx.x == 0) {
        uint run = 0;
        for (int i = 0; i < 64; ++i) { uint v = dcnt[i]; dcnt[i] = run; run += v; }
    }
}

__global__ void k_dfill(const uint* __restrict__ row_ptr, uint* __restrict__ dcur,
                        uint* __restrict__ perm, int N) {
    __shared__ uint lh[64];
    __shared__ uint lbase[64];
    int tid = threadIdx.x;
    if (tid < 64) lh[tid] = 0u;
    __syncthreads();
    int i = blockIdx.x * 256 + tid;
    uint d = 63u;
    if (i < N) {
        d = row_ptr[i + 1] - row_ptr[i];
        if (d > 63u) d = 63u;
        atomicAdd(&lh[d], 1u);          // phase A: block count (LDS)
    }
    __syncthreads();
    if (tid < 64) {
        uint c = lh[tid];
        lbase[tid] = c ? atomicAdd(&dcur[tid], c) : 0u;  // claim base range
        lh[tid] = 0u;                    // reuse as rank counter
    }
    __syncthreads();
    if (i < N) {
        uint r = atomicAdd(&lh[d], 1u);  // phase C: rank within block (LDS)
        perm[lbase[d] + r] = (uint)i;
    }
}

__global__ void k_cvt(const float4* __restrict__ in, ushort4* __restrict__ outp, int n4) {
    int i = blockIdx.x * 256 + threadIdx.x;
    if (i >= n4) return;
    float4 v = in[i];
    ushort4 o;
    o.x = f2h(v.x); o.y = f2h(v.y); o.z = f2h(v.z); o.w = f2h(v.w);
    outp[i] = o;
}

// ---------------- g-projection pre-pack: Wgf[k][f] = sum_c Wq[k,c]*We[f,c] ----
__global__ void k_packg(const float* __restrict__ Wq, const float* __restrict__ bq,
                        const float* __restrict__ We, float* __restrict__ Wgf,
                        float* __restrict__ bgf, int C) {
    int id = blockIdx.x * 256 + threadIdx.x;
    if (id < 2048) {
        int k = id >> 4, f = id & 15;
        float s = 0.f;
        for (int c = 0; c < C; ++c) s = fmaf(Wq[k * C + c], We[f * C + c], s);
        Wgf[id] = s;              // layout [k*16+f]
    } else if (id < 2064) {
        int f = id - 2048;
        float s = 0.f;
        for (int c = 0; c < C; ++c) s = fmaf(bq[c], We[f * C + c], s);
        bgf[f] = s;
    }
}

// ---------------- weight packing (cols: Wq|Wk|Wv|Ws|Wg -> 4C+16) -------------
__global__ void k_packw(const float* __restrict__ Wq, const float* __restrict__ Wk,
                        const float* __restrict__ Wv, const float* __restrict__ Ws,
                        const float* __restrict__ Wgf, ushort* __restrict__ Bp, int C) {
    int nct = (4 * C + 16) >> 4;
    int total = 4 * nct * 512;
    int id = blockIdx.x * 256 + threadIdx.x;
    if (id >= total) return;
    int j = id & 7;
    int rest = id >> 3;
    int lane = rest & 63;
    rest >>= 6;
    int ct = rest % nct;
    int kt = rest / nct;
    int k = kt * 32 + ((lane >> 4) << 3) + j;
    int c = (ct << 4) + (lane & 15);
    float w;
    if (c < 4 * C) {
        int mat = c / C, cc = c % C;
        const float* W = (mat == 0) ? Wq : (mat == 1) ? Wk : (mat == 2) ? Wv : Ws;
        w = W[k * C + cc];
    } else {
        w = Wgf[k * 16 + (c - 4 * C)];
    }
    Bp[id] = f2h(w);
}

__global__ void k_bias(const float* __restrict__ bq, const float* __restrict__ bk,
                       const float* __restrict__ bv, const float* __restrict__ bs,
                       const float* __restrict__ bgf, float* __restrict__ outp, int C) {
    int c = blockIdx.x * 256 + threadIdx.x;
    if (c >= 4 * C + 16) return;
    float v;
    if (c < 4 * C) {
        int mat = c / C, cc = c % C;
        const float* b = (mat == 0) ? bq : (mat == 1) ? bk : (mat == 2) ? bv : bs;
        v = b[cc];
    } else {
        v = bgf[c - 4 * C];
    }
    outp[c] = v;
}

// ---------------- fused QKVSG GEMM (f16 MFMA), B-resident row-tile loop ------
// A: [N,128] f16. Cols [0,3C)->H (q|k|v), [3C,4C)->S (skip), [4C,4C+16)->g.
__global__ __launch_bounds__(256, 4) void k_gemm(const ushort* __restrict__ A,
                                                 const ushort* __restrict__ Bp,
                                                 const float* __restrict__ bias,
                                                 ushort* __restrict__ H,
                                                 ushort* __restrict__ S,
                                                 ushort* __restrict__ g,
                                                 int C, int mt_total) {
    constexpr int RT = 8;
    int fourC = 4 * C, threeC = 3 * C;
    int P = fourC + 16;
    int nct = P >> 4;
    int lane = threadIdx.x & 63;
    int wave = threadIdx.x >> 6;
    int quad = lane >> 4;
    int r = lane & 15;
    int c0 = (blockIdx.x << 8) + (wave << 6);
    int ct0 = c0 >> 4;
    if (ct0 >= nct) return;

    // B fragments: loaded once, register-resident across all row-tiles
    f16x8 bf[16];
#pragma unroll
    for (int kk = 0; kk < 4; ++kk)
#pragma unroll
        for (int i = 0; i < 4; ++i) {
            if (ct0 + i < nct)
                bf[kk * 4 + i] = *(const f16x8*)(Bp + ((size_t)((kk * nct + ct0 + i) << 6) + lane) * 8);
            else
                bf[kk * 4 + i] = __builtin_bit_cast(f16x8, (uint4){0u, 0u, 0u, 0u});
        }

    float bi4[4];
#pragma unroll
    for (int i = 0; i < 4; ++i) {
        int cc = c0 + (i << 4) + r;
        bi4[i] = (cc < P) ? bias[cc] : 0.f;
    }

    int mt0 = blockIdx.y * RT;
    int mt_end = mt0 + RT;
    if (mt_end > mt_total) mt_end = mt_total;

    for (int mt = mt0; mt < mt_end; ++mt) {
        int m0 = mt << 4;
        const ushort* arow = A + (size_t)(m0 + r) * 128 + (quad << 3);

        f32x4 acc[4];
#pragma unroll
        for (int i = 0; i < 4; ++i) acc[i] = (f32x4){0.f, 0.f, 0.f, 0.f};

#pragma unroll
        for (int kk = 0; kk < 4; ++kk) {
            f16x8 a = *(const f16x8*)(arow + kk * 32);
#pragma unroll
            for (int i = 0; i < 4; ++i)
                if (ct0 + i < nct)
                    acc[i] = __builtin_amdgcn_mfma_f32_16x16x32_f16(a, bf[kk * 4 + i], acc[i], 0, 0, 0);
        }

        // R9-proven scatter epilogue (C-layout: col=c0+i*16+r, row=quad*4+reg)
#pragma unroll
        for (int i = 0; i < 4; ++i) {
            int cc = c0 + (i << 4) + r;
            if (cc >= P) continue;
#pragma unroll
            for (int reg = 0; reg < 4; ++reg) {
                int rr = m0 + (quad << 2) + reg;
                ushort val = f2h(acc[i][reg] + bi4[i]);
                if (cc < threeC)      H[(size_t)rr * threeC + cc] = val;
                else if (cc < fourC)  S[(size_t)rr * C + (cc - threeC)] = val;
                else                  g[(size_t)rr * 16 + (cc - fourC)] = val;
            }
        }
    }
}

// ---------------- edge pass 1: logits -> e (per edge), w,l (per node) --------
// Gathers K + eattr only. g buffer is read early (g = We^T q) and overwritten
// late with w = sum e*attr (f16) -- same group, same row, read-before-write.
// node = perm[slot]: degree-sorted so co-resident groups have equal trip count.
template <int C, int GSIZE>
__global__ __launch_bounds__(256, 6) void k_edge1(const ushort* __restrict__ H,
                                                  ushort* g,   // in: g, out: w
                                                  const uint* __restrict__ row_ptr,
                                                  const int2* __restrict__ srcid,
                                                  const float* __restrict__ eattr,
                                                  const uint* __restrict__ perm,
                                                  ushort* __restrict__ ebuf,
                                                  float* __restrict__ lbuf, int N) {
    constexpr int VR = C / GSIZE;        // 8
    constexpr int TH = 3 * C;
    constexpr int GPB = 256 / GSIZE;
    const float scale = (C == 128) ? 0.08838834764831843f : 0.0625f;  // 1/sqrt(C)
    const float foldk = 16.0f / (float)GSIZE;  // attr replication compensation

    int lane = threadIdx.x & (GSIZE - 1);
    int grp = threadIdx.x / GSIZE;
    int f = lane & 15;
    int slot = blockIdx.x * GPB + grp;
    if (slot >= N) return;
    int node = (int)perm[slot];
    int lvr = lane * VR;

    uint4 qv = *(const uint4*)(H + (size_t)node * TH + lvr);
    h16x2 q0 = bch2(qv.x), q1 = bch2(qv.y), q2 = bch2(qv.z), q3 = bch2(qv.w);
    float fg = foldk * h2f(g[(size_t)node * 16 + f]);
    uint beg = row_ptr[node], end = row_ptr[node + 1];

    float l = 0.f, w = 0.f;
    for (uint t = beg; t < end; t += 4) {
        uint t1 = (t + 1 < end) ? t + 1 : t;   // replicate-last; masked by e=0
        uint t2 = (t + 2 < end) ? t + 2 : t;
        uint t3 = (t + 3 < end) ? t + 3 : t;
        int2 se0 = srcid[t], se1 = srcid[t1], se2 = srcid[t2], se3 = srcid[t3];
        float at0 = eattr[(size_t)se0.y * 16 + f];
        float at1 = eattr[(size_t)se1.y * 16 + f];
        float at2 = eattr[(size_t)se2.y * 16 + f];
        float at3 = eattr[(size_t)se3.y * 16 + f];
        uint4 k0 = *(const uint4*)(H + (size_t)se0.x * TH + C + lvr);
        uint4 k1 = *(const uint4*)(H + (size_t)se1.x * TH + C + lvr);
        uint4 k2 = *(const uint4*)(H + (size_t)se2.x * TH + C + lvr);
        uint4 k3 = *(const uint4*)(H + (size_t)se3.x * TH + C + lvr);

        float p0 = at0 * fg, p1 = at1 * fg, p2 = at2 * fg, p3 = at3 * fg;
        p0 = FDOT2(q0, bch2(k0.x), p0); p0 = FDOT2(q1, bch2(k0.y), p0);
        p0 = FDOT2(q2, bch2(k0.z), p0); p0 = FDOT2(q3, bch2(k0.w), p0);
        p1 = FDOT2(q0, bch2(k1.x), p1); p1 = FDOT2(q1, bch2(k1.y), p1);
        p1 = FDOT2(q2, bch2(k1.z), p1); p1 = FDOT2(q3, bch2(k1.w), p1);
        p2 = FDOT2(q0, bch2(k2.x), p2); p2 = FDOT2(q1, bch2(k2.y), p2);
        p2 = FDOT2(q2, bch2(k2.z), p2); p2 = FDOT2(q3, bch2(k2.w), p2);
        p3 = FDOT2(q0, bch2(k3.x), p3); p3 = FDOT2(q1, bch2(k3.y), p3);
        p3 = FDOT2(q2, bch2(k3.z), p3); p3 = FDOT2(q3, bch2(k3.w), p3);

        p0 += __shfl_xor(p0, 1); p1 += __shfl_xor(p1, 1);
        p2 += __shfl_xor(p2, 1); p3 += __shfl_xor(p3, 1);
        p0 += __shfl_xor(p0, 2); p1 += __shfl_xor(p1, 2);
        p2 += __shfl_xor(p2, 2); p3 += __shfl_xor(p3, 2);
        p0 += __shfl_xor(p0, 4); p1 += __shfl_xor(p1, 4);
        p2 += __shfl_xor(p2, 4); p3 += __shfl_xor(p3, 4);
        p0 += __shfl_xor(p0, 8); p1 += __shfl_xor(p1, 8);
        p2 += __shfl_xor(p2, 8); p3 += __shfl_xor(p3, 8);
        if (GSIZE == 32) {
            p0 += __shfl_xor(p0, 16); p1 += __shfl_xor(p1, 16);
            p2 += __shfl_xor(p2, 16); p3 += __shfl_xor(p3, 16);
        }
        float e0 = __expf(p0 * scale);
        float e1 = (t + 1 < end) ? __expf(p1 * scale) : 0.f;
        float e2 = (t + 2 < end) ? __expf(p2 * scale) : 0.f;
        float e3 = (t + 3 < end) ? __expf(p3 * scale) : 0.f;
        l += (e0 + e1) + (e2 + e3);
        w = fmaf(e0, at0, w); w = fmaf(e1, at1, w);
        w = fmaf(e2, at2, w); w = fmaf(e3, at3, w);
        if (lane < 4) {                      // lanes 0..3 store valid slots only
            uint tj = t + lane;
            if (tj < end) {
                float ee = (lane == 0) ? e0 : (lane == 1) ? e1 : (lane == 2) ? e2 : e3;
                ebuf[tj] = f2h(ee);
            }
        }
    }
    if (lane < 16) g[(size_t)node * 16 + lane] = f2h(w);  // overwrite g with w
    if (lane == 0) lbuf[node] = l;
}

// ---------------- edge pass 2: out = (sum e*v + w.We)/l + skip ---------------
// Gathers V only; batch-4 (R12-proven). node = perm[slot].
template <int C, int GSIZE, bool RELU>
__global__ __launch_bounds__(256, 6) void k_edge2(const ushort* __restrict__ H,
                                                  ushort* __restrict__ S,
                                                  const uint* __restrict__ row_ptr,
                                                  const int2* __restrict__ srcid,
                                                  const ushort* __restrict__ ebuf,
                                                  const ushort* __restrict__ wbuf,
                                                  const float* __restrict__ lbuf,
                                                  const uint* __restrict__ perm,
                                                  const float* __restrict__ We, int N) {
    constexpr int VR = C / GSIZE;        // 8
    constexpr int TH = 3 * C;
    constexpr int GPB = 256 / GSIZE;
    __shared__ float swex[GPB][17];      // +1 pad: conflict-free group reads

    int lane = threadIdx.x & (GSIZE - 1);
    int grp = threadIdx.x / GSIZE;
    int slot = blockIdx.x * GPB + grp;
    if (slot >= N) return;
    int node = (int)perm[slot];
    int lvr = lane * VR;
    uint beg = row_ptr[node], end = row_ptr[node + 1];

    ushort* srow = S + (size_t)node * C + lvr;
    uint4 skv = *(const uint4*)srow;                     // early skip load
    if (lane < 16) swex[grp][lane] = h2f(wbuf[(size_t)node * 16 + lane]);
    float l = lbuf[node];

    f32x2 acc[4];
#pragma unroll
    for (int j = 0; j < 4; ++j) acc[j] = (f32x2){0.f, 0.f};

    for (uint t = beg; t < end; t += 4) {
        uint t1 = (t + 1 < end) ? t + 1 : t;
        uint t2 = (t + 2 < end) ? t + 2 : t;
        uint t3 = (t + 3 < end) ? t + 3 : t;
        int s0 = srcid[t].x, s1 = srcid[t1].x, s2 = srcid[t2].x, s3 = srcid[t3].x;
        float e0 = h2f(ebuf[t]);
        float e1 = (t + 1 < end) ? h2f(ebuf[t1]) : 0.f;
        float e2 = (t + 2 < end) ? h2f(ebuf[t2]) : 0.f;
        float e3 = (t + 3 < end) ? h2f(ebuf[t3]) : 0.f;
        uint4 v0 = *(const uint4*)(H + (size_t)s0 * TH + 2 * C + lvr);
        uint4 v1 = *(const uint4*)(H + (size_t)s1 * TH + 2 * C + lvr);
        uint4 v2 = *(const uint4*)(H + (size_t)s2 * TH + 2 * C + lvr);
        uint4 v3 = *(const uint4*)(H + (size_t)s3 * TH + 2 * C + lvr);
        f32x2 eb;
        eb = (f32x2){e0, e0};
        acc[0] = __builtin_elementwise_fma(cvt2(v0.x), eb, acc[0]);
        acc[1] = __builtin_elementwise_fma(cvt2(v0.y), eb, acc[1]);
        acc[2] = __builtin_elementwise_fma(cvt2(v0.z), eb, acc[2]);
        acc[3] = __builtin_elementwise_fma(cvt2(v0.w), eb, acc[3]);
        eb = (f32x2){e1, e1};
        acc[0] = __builtin_elementwise_fma(cvt2(v1.x), eb, acc[0]);
        acc[1] = __builtin_elementwise_fma(cvt2(v1.y), eb, acc[1]);
        acc[2] = __builtin_elementwise_fma(cvt2(v1.z), eb, acc[2]);
        acc[3] = __builtin_elementwise_fma(cvt2(v1.w), eb, acc[3]);
        eb = (f32x2){e2, e2};
        acc[0] = __builtin_elementwise_fma(cvt2(v2.x), eb, acc[0]);
        acc[1] = __builtin_elementwise_fma(cvt2(v2.y), eb, acc[1]);
        acc[2] = __builtin_elementwise_fma(cvt2(v2.z), eb, acc[2]);
        acc[3] = __builtin_elementwise_fma(cvt2(v2.w), eb, acc[3]);
        eb = (f32x2){e3, e3};
        acc[0] = __builtin_elementwise_fma(cvt2(v3.x), eb, acc[0]);
        acc[1] = __builtin_elementwise_fma(cvt2(v3.y), eb, acc[1]);
        acc[2] = __builtin_elementwise_fma(cvt2(v3.z), eb, acc[2]);
        acc[3] = __builtin_elementwise_fma(cvt2(v3.w), eb, acc[3]);
    }

    float inv = 1.f / (l + 1e-16f);   // empty node: acc=w=0 -> out = skip
    f32x2 ew[4];
#pragma unroll
    for (int j = 0; j < 4; ++j) ew[j] = (f32x2){0.f, 0.f};
#pragma unroll
    for (int f2i = 0; f2i < 16; ++f2i) {
        float wfs = swex[grp][f2i];
        f32x2 wf = (f32x2){wfs, wfs};
        const f32x4* wrow = (const f32x4*)(We + f2i * C + lvr);
        f32x4 c0 = wrow[0], c1 = wrow[1];
        ew[0] = __builtin_elementwise_fma(c0.lo, wf, ew[0]);
        ew[1] = __builtin_elementwise_fma(c0.hi, wf, ew[1]);
        ew[2] = __builtin_elementwise_fma(c1.lo, wf, ew[2]);
        ew[3] = __builtin_elementwise_fma(c1.hi, wf, ew[3]);
    }
    const uint* sp = (const uint*)&skv;
    uint4 ov;
    uint* op = (uint*)&ov;
#pragma unroll
    for (int hh = 0; hh < 4; ++hh) {
        f32x2 sk = cvt2(sp[hh]);
        float o0 = (acc[hh].x + ew[hh].x) * inv + sk.x;
        float o1 = (acc[hh].y + ew[hh].y) * inv + sk.y;
        if (RELU) { o0 = fmaxf(o0, 0.f); o1 = fmaxf(o1, 0.f); }
        op[hh] = (uint)f2h(o0) | ((uint)f2h(o1) << 16);
    }
    *(uint4*)srow = ov;
}

// ---------------- classifier: out[N,10] = h3(f16) @ Wc + bc ----------------
__global__ void k_cls(const ushort* __restrict__ h, const float* __restrict__ Wc,
                      const float* __restrict__ bc, float* __restrict__ outp, int N) {
    int t = blockIdx.x * 256 + threadIdx.x;
    int node = t >> 4;
    int c = t & 15;
    if (node >= N || c >= 10) return;
    const ushort* hr = h + (size_t)node * 256;
    float acc = 0.f;
#pragma unroll 4
    for (int k4 = 0; k4 < 64; ++k4) {
        uint2 u = *(const uint2*)(hr + k4 * 4);
        f32x2 a01 = cvt2(u.x);
        f32x2 a23 = cvt2(u.y);
        int kb = k4 * 4;
        acc = fmaf(a01.x, Wc[(kb + 0) * 10 + c], acc);
        acc = fmaf(a01.y, Wc[(kb + 1) * 10 + c], acc);
        acc = fmaf(a23.x, Wc[(kb + 2) * 10 + c], acc);
        acc = fmaf(a23.y, Wc[(kb + 3) * 10 + c], acc);
    }
    outp[node * 10 + c] = acc + bc[c];
}

// ---------------- launch ----------------
extern "C" void kernel_launch(void* const* d_in, const int* in_sizes, int n_in,
                              void* d_out, int out_size, void* d_ws, size_t ws_size,
                              hipStream_t stream) {
    const float* x = (const float*)d_in[0];
    const int* ei = (const int*)d_in[1];
    const float* eattr = (const float*)d_in[2];
    const int N = in_sizes[0] / 128;
    const int E = in_sizes[1] / 2;

    const float* Wq[3], *bq[3], *Wk[3], *bk[3], *Wv[3], *bv[3], *We[3], *Ws[3], *bs[3];
    for (int li = 0; li < 3; ++li) {
        int base = 3 + li * 9;
        Wq[li] = (const float*)d_in[base + 0];
        bq[li] = (const float*)d_in[base + 1];
        Wk[li] = (const float*)d_in[base + 2];
        bk[li] = (const float*)d_in[base + 3];
        Wv[li] = (const float*)d_in[base + 4];
        bv[li] = (const float*)d_in[base + 5];
        We[li] = (const float*)d_in[base + 6];
        Ws[li] = (const float*)d_in[base + 7];
        bs[li] = (const float*)d_in[base + 8];
    }
    const float* Wc = (const float*)d_in[30];
    const float* bc = (const float*)d_in[31];

    // workspace carve (~244 MB -- R12 budget + perm 0.4MB + dcnt)
    size_t off = 0;
    char* base = (char*)d_ws;
    auto alloc = [&](size_t bytes) -> void* {
        void* p = base + off;
        off = (off + bytes + 255) & ~(size_t)255;
        return p;
    };
    ushort* SA = (ushort*)alloc((size_t)N * 256 * 2);   // skip/out ping
    ushort* SB = (ushort*)alloc((size_t)N * 128 * 2);   // pong (also xb)
    ushort* H  = (ushort*)alloc((size_t)N * 768 * 2);   // q|k|v (max 3C)
    ushort* gbuf = (ushort*)alloc((size_t)N * 16 * 2);  // g = We.q; then w
    ushort* Bp = (ushort*)alloc(140000 * 2);            // packed weights
    float* biasc = (float*)alloc(1040 * 4);
    float* Wgf = (float*)alloc(2048 * 4);
    float* bgf = (float*)alloc(16 * 4);
    uint* row_ptr = (uint*)alloc((size_t)(N + 1) * 4);
    uint* counts = (uint*)alloc((size_t)N * 4);
    uint* cursor = (uint*)alloc((size_t)N * 4);
    uint* bsum = (uint*)alloc(1024 * 4);
    int2* srcid = (int2*)alloc((size_t)E * 8);          // CSR {src, eidx}
    ushort* ebuf = (ushort*)alloc((size_t)E * 2);       // pass1 -> pass2 e (f16)
    uint* perm = (uint*)alloc((size_t)N * 4);           // degree-sorted nodes
    uint* dcnt = (uint*)alloc(64 * 4);                  // degree buckets

    ushort* xb = SB;             // alias: xb dead after layer-1 GEMM
    float* lbuf = (float*)counts; // alias: counts dead after CSR build

    int nb = (N + 1023) / 1024;

    // CSR build
    k_zero<<<(N + 255) / 256, 256, 0, stream>>>(counts, N);
    k_zero<<<(N + 255) / 256, 256, 0, stream>>>(cursor, N);
    k_hist<<<(E + 255) / 256, 256, 0, stream>>>(ei + E, counts, E, N);
    k_scan1<<<nb, 256, 0, stream>>>(counts, bsum, N);
    k_scan2<<<1, 64, 0, stream>>>(bsum, nb);
    k_scan3<<<nb, 256, 0, stream>>>(counts, bsum, row_ptr, N, E);
    k_fill<<<(E + 255) / 256, 256, 0, stream>>>(ei, row_ptr, cursor, srcid, E, N);

    // degree counting sort -> perm (two-level, contention-free)
    k_zero<<<1, 64, 0, stream>>>(dcnt, 64);
    k_dhist<<<(N + 255) / 256, 256, 0, stream>>>(row_ptr, dcnt, N);
    k_dscan<<<1, 64, 0, stream>>>(dcnt);
    k_dfill<<<(N + 255) / 256, 256, 0, stream>>>(row_ptr, dcnt, perm, N);

    // x -> f16
    int n4 = N * 128 / 4;
    k_cvt<<<(n4 + 255) / 256, 256, 0, stream>>>((const float4*)x, (ushort4*)xb, n4);

    int mt_total = N / 16;    // N divisible by 16
    for (int li = 0; li < 3; ++li) {
        int C = (li == 2) ? 256 : 128;
        int P = 4 * C + 16;
        int packTotal = 4 * (P >> 4) * 512;
        const ushort* A = (li == 0) ? xb : (li == 1) ? SA : SB;
        ushort* Sout = (li == 1) ? SB : SA;

        k_packg<<<9, 256, 0, stream>>>(Wq[li], bq[li], We[li], Wgf, bgf, C);
        k_packw<<<(packTotal + 255) / 256, 256, 0, stream>>>(Wq[li], Wk[li], Wv[li], Ws[li], Wgf, Bp, C);
        k_bias<<<(P + 255) / 256, 256, 0, stream>>>(bq[li], bk[li], bv[li], bs[li], bgf, biasc, C);
        k_gemm<<<dim3((P + 255) / 256, (mt_total + 7) / 8), 256, 0, stream>>>(A, Bp, biasc, H, Sout, gbuf, C, mt_total);
        if (li == 2) {
            k_edge1<256, 32><<<(N * 32 + 255) / 256, 256, 0, stream>>>(H, gbuf, row_ptr, srcid, eattr, perm, ebuf, lbuf, N);
            k_edge2<256, 32, false><<<(N * 32 + 255) / 256, 256, 0, stream>>>(H, Sout, row_ptr, srcid, ebuf, gbuf, lbuf, perm, We[li], N);
        } else {
            k_edge1<128, 16><<<(N * 16 + 255) / 256, 256, 0, stream>>>(H, gbuf, row_ptr, srcid, eattr, perm, ebuf, lbuf, N);
            k_edge2<128, 16, true><<<(N * 16 + 255) / 256, 256, 0, stream>>>(H, Sout, row_ptr, srcid, ebuf, gbuf, lbuf, perm, We[li], N);
        }
    }

    // classifier (layer-3 output is in SA)
    k_cls<<<(N * 16 + 255) / 256, 256, 0, stream>>>(SA, Wc, bc, (float*)d_out, N);
}

// Round 11
// 944.748 us; speedup vs baseline: 1.8021x; 1.0756x over previous
//
#include <hip/hip_runtime.h>
#include <math.h>

// TrfEdgeNetRand: 3x TransformerConv(heads=1) + ReLU + classifier on MI355X.
// R17: R12's B-resident gemm + FUSED f16 batch-2 edge kernel.
//  - R16 post-mortem: degree-sort perm = zero gain on edge2 (99.5 vs 100us;
//    FETCH 222->239, locality loss ate the divergence win). Third falsified
//    lever on k_edge2 -> batch-4/(256,6)/node-per-group is locally optimal.
//  - Ledger check: R6 fused edge (1030) vs R9 split (1054) -> the SPLIT cost
//    ~24us (no FETCH reduction materialized; extra launches + srcid x2 +
//    ebuf/w/l roundtrips). f16+fdot2 (VALU 41->30%) was never tested fused
//    at a spill-free batch (R7 bundled it with batch-4 -> spill).
//  - This round: R7's fused body (PASSED, absmax 0.0039) at batch-2 = R6's
//    proven 36-VGPR footprint + proven f16 datapath. No perm, no sort.
//  - k_gemm and all CSR/pack/cls kernels byte-identical to R12.

typedef unsigned int uint;
typedef unsigned short ushort;
typedef _Float16 f16x8 __attribute__((ext_vector_type(8)));
typedef _Float16 h16x2 __attribute__((ext_vector_type(2)));
typedef float f32x4 __attribute__((ext_vector_type(4)));
typedef float f32x2 __attribute__((ext_vector_type(2)));

__device__ __forceinline__ ushort f2h(float f) {
    return __builtin_bit_cast(ushort, (_Float16)f);   // v_cvt_f16_f32 (RNE)
}
__device__ __forceinline__ float h2f(ushort h) {
    return (float)__builtin_bit_cast(_Float16, h);
}
__device__ __forceinline__ h16x2 bch2(uint u) { return __builtin_bit_cast(h16x2, u); }
__device__ __forceinline__ f32x2 cvt2(uint u) {
    h16x2 h = bch2(u);
    return (f32x2){(float)h.x, (float)h.y};
}

#if __has_builtin(__builtin_amdgcn_fdot2)
#define FDOT2(a, b, c) __builtin_amdgcn_fdot2((a), (b), (c), false)
#else
__device__ __forceinline__ float fdot2_sw(h16x2 a, h16x2 b, float c) {
    return fmaf((float)a.x, (float)b.x, fmaf((float)a.y, (float)b.y, c));
}
#define FDOT2(a, b, c) fdot2_sw((a), (b), (c))
#endif

// ---------------- utility kernels ----------------
__global__ void k_zero(uint* p, int n) {
    int i = blockIdx.x * 256 + threadIdx.x;
    if (i < n) p[i] = 0u;
}

__global__ void k_hist(const int* __restrict__ dst, uint* __restrict__ counts, int E, int N) {
    int e = blockIdx.x * 256 + threadIdx.x;
    if (e < E) {
        int d = dst[e];
        d = (d < 0) ? 0 : (d >= N ? N - 1 : d);
        atomicAdd(&counts[d], 1u);
    }
}

__global__ void k_scan1(const uint* __restrict__ counts, uint* __restrict__ bsum, int n) {
    __shared__ uint sm[256];
    int tid = threadIdx.x;
    int base = blockIdx.x * 1024 + tid * 4;
    uint s = 0;
#pragma unroll
    for (int j = 0; j < 4; ++j)
        if (base + j < n) s += counts[base + j];
    sm[tid] = s;
    __syncthreads();
    for (int d = 128; d > 0; d >>= 1) {
        if (tid < d) sm[tid] += sm[tid + d];
        __syncthreads();
    }
    if (tid == 0) bsum[blockIdx.x] = sm[0];
}

__global__ void k_scan2(uint* bsum, int nb) {
    if (threadIdx.x == 0 && blockIdx.x == 0) {
        uint run = 0;
        for (int i = 0; i < nb; ++i) { uint v = bsum[i]; bsum[i] = run; run += v; }
    }
}

__global__ void k_scan3(const uint* __restrict__ counts, const uint* __restrict__ bsum,
                        uint* __restrict__ row_ptr, int n, int E) {
    __shared__ uint sm[256];
    int tid = threadIdx.x;
    int base = blockIdx.x * 1024 + tid * 4;
    uint local[4];
    uint s = 0;
#pragma unroll
    for (int j = 0; j < 4; ++j) {
        local[j] = (base + j < n) ? counts[base + j] : 0u;
        s += local[j];
    }
    sm[tid] = s;
    __syncthreads();
    for (int d = 1; d < 256; d <<= 1) {
        uint v = (tid >= d) ? sm[tid - d] : 0u;
        __syncthreads();
        sm[tid] += v;
        __syncthreads();
    }
    uint run = sm[tid] - s + bsum[blockIdx.x];
#pragma unroll
    for (int j = 0; j < 4; ++j)
        if (base + j < n) { row_ptr[base + j] = run; run += local[j]; }
    if (blockIdx.x == 0 && tid == 0) row_ptr[n] = (uint)E;
}

__global__ void k_fill(const int* __restrict__ ei, const uint* __restrict__ row_ptr,
                       uint* __restrict__ cursor, int2* __restrict__ srcid, int E, int N) {
    int e = blockIdx.x * 256 + threadIdx.x;
    if (e >= E) return;
    int s = ei[e];
    int d = ei[E + e];
    s = (s < 0) ? 0 : (s >= N ? N - 1 : s);
    d = (d < 0) ? 0 : (d >= N ? N - 1 : d);
    uint idx = row_ptr[d] + atomicAdd(&cursor[d], 1u);
    srcid[idx] = make_int2(s, e);
}

__global__ void k_cvt(const float4* __restrict__ in, ushort4* __restrict__ outp, int n4) {
    int i = blockIdx.x * 256 + threadIdx.x;
    if (i >= n4) return;
    float4 v = in[i];
    ushort4 o;
    o.x = f2h(v.x); o.y = f2h(v.y); o.z = f2h(v.z); o.w = f2h(v.w);
    outp[i] = o;
}

// ---------------- g-projection pre-pack: Wgf[k][f] = sum_c Wq[k,c]*We[f,c] ----
__global__ void k_packg(const float* __restrict__ Wq, const float* __restrict__ bq,
                        const float* __restrict__ We, float* __restrict__ Wgf,
                        float* __restrict__ bgf, int C) {
    int id = blockIdx.x * 256 + threadIdx.x;
    if (id < 2048) {
        int k = id >> 4, f = id & 15;
        float s = 0.f;
        for (int c = 0; c < C; ++c) s = fmaf(Wq[k * C + c], We[f * C + c], s);
        Wgf[id] = s;              // layout [k*16+f]
    } else if (id < 2064) {
        int f = id - 2048;
        float s = 0.f;
        for (int c = 0; c < C; ++c) s = fmaf(bq[c], We[f * C + c], s);
        bgf[f] = s;
    }
}

// ---------------- weight packing (cols: Wq|Wk|Wv|Ws|Wg -> 4C+16) -------------
__global__ void k_packw(const float* __restrict__ Wq, const float* __restrict__ Wk,
                        const float* __restrict__ Wv, const float* __restrict__ Ws,
                        const float* __restrict__ Wgf, ushort* __restrict__ Bp, int C) {
    int nct = (4 * C + 16) >> 4;
    int total = 4 * nct * 512;
    int id = blockIdx.x * 256 + threadIdx.x;
    if (id >= total) return;
    int j = id & 7;
    int rest = id >> 3;
    int lane = rest & 63;
    rest >>= 6;
    int ct = rest % nct;
    int kt = rest / nct;
    int k = kt * 32 + ((lane >> 4) << 3) + j;
    int c = (ct << 4) + (lane & 15);
    float w;
    if (c < 4 * C) {
        int mat = c / C, cc = c % C;
        const float* W = (mat == 0) ? Wq : (mat == 1) ? Wk : (mat == 2) ? Wv : Ws;
        w = W[k * C + cc];
    } else {
        w = Wgf[k * 16 + (c - 4 * C)];
    }
    Bp[id] = f2h(w);
}

__global__ void k_bias(const float* __restrict__ bq, const float* __restrict__ bk,
                       const float* __restrict__ bv, const float* __restrict__ bs,
                       const float* __restrict__ bgf, float* __restrict__ outp, int C) {
    int c = blockIdx.x * 256 + threadIdx.x;
    if (c >= 4 * C + 16) return;
    float v;
    if (c < 4 * C) {
        int mat = c / C, cc = c % C;
        const float* b = (mat == 0) ? bq : (mat == 1) ? bk : (mat == 2) ? bv : bs;
        v = b[cc];
    } else {
        v = bgf[c - 4 * C];
    }
    outp[c] = v;
}

// ---------------- fused QKVSG GEMM (f16 MFMA), B-resident row-tile loop ------
// A: [N,128] f16. Cols [0,3C)->H (q|k|v), [3C,4C)->S (skip), [4C,4C+16)->g.
__global__ __launch_bounds__(256, 4) void k_gemm(const ushort* __restrict__ A,
                                                 const ushort* __restrict__ Bp,
                                                 const float* __restrict__ bias,
                                                 ushort* __restrict__ H,
                                                 ushort* __restrict__ S,
                                                 ushort* __restrict__ g,
                                                 int C, int mt_total) {
    constexpr int RT = 8;
    int fourC = 4 * C, threeC = 3 * C;
    int P = fourC + 16;
    int nct = P >> 4;
    int lane = threadIdx.x & 63;
    int wave = threadIdx.x >> 6;
    int quad = lane >> 4;
    int r = lane & 15;
    int c0 = (blockIdx.x << 8) + (wave << 6);
    int ct0 = c0 >> 4;
    if (ct0 >= nct) return;

    // B fragments: loaded once, register-resident across all row-tiles
    f16x8 bf[16];
#pragma unroll
    for (int kk = 0; kk < 4; ++kk)
#pragma unroll
        for (int i = 0; i < 4; ++i) {
            if (ct0 + i < nct)
                bf[kk * 4 + i] = *(const f16x8*)(Bp + ((size_t)((kk * nct + ct0 + i) << 6) + lane) * 8);
            else
                bf[kk * 4 + i] = __builtin_bit_cast(f16x8, (uint4){0u, 0u, 0u, 0u});
        }

    float bi4[4];
#pragma unroll
    for (int i = 0; i < 4; ++i) {
        int cc = c0 + (i << 4) + r;
        bi4[i] = (cc < P) ? bias[cc] : 0.f;
    }

    int mt0 = blockIdx.y * RT;
    int mt_end = mt0 + RT;
    if (mt_end > mt_total) mt_end = mt_total;

    for (int mt = mt0; mt < mt_end; ++mt) {
        int m0 = mt << 4;
        const ushort* arow = A + (size_t)(m0 + r) * 128 + (quad << 3);

        f32x4 acc[4];
#pragma unroll
        for (int i = 0; i < 4; ++i) acc[i] = (f32x4){0.f, 0.f, 0.f, 0.f};

#pragma unroll
        for (int kk = 0; kk < 4; ++kk) {
            f16x8 a = *(const f16x8*)(arow + kk * 32);
#pragma unroll
            for (int i = 0; i < 4; ++i)
                if (ct0 + i < nct)
                    acc[i] = __builtin_amdgcn_mfma_f32_16x16x32_f16(a, bf[kk * 4 + i], acc[i], 0, 0, 0);
        }

        // R9-proven scatter epilogue (C-layout: col=c0+i*16+r, row=quad*4+reg)
#pragma unroll
        for (int i = 0; i < 4; ++i) {
            int cc = c0 + (i << 4) + r;
            if (cc >= P) continue;
#pragma unroll
            for (int reg = 0; reg < 4; ++reg) {
                int rr = m0 + (quad << 2) + reg;
                ushort val = f2h(acc[i][reg] + bi4[i]);
                if (cc < threeC)      H[(size_t)rr * threeC + cc] = val;
                else if (cc < fourC)  S[(size_t)rr * C + (cc - threeC)] = val;
                else                  g[(size_t)rr * 16 + (cc - fourC)] = val;
            }
        }
    }
}

// ---------------- fused edge attention: GSIZE-lane group per node ------------
// H: [N,3C] f16 (q|k|v). S: skip on entry, output on exit. g: [N,16] f16.
// Batch-2 (R6's proven 36-VGPR footprint) with f16/fdot2 datapath (R7 math,
// which passed: absmax 0.0039). Plain exp: logits |alpha|<~2 by construction.
template <int C, int GSIZE, bool RELU>
__global__ __launch_bounds__(256, 6) void k_edge(const ushort* __restrict__ H,
                                                 ushort* __restrict__ S,
                                                 const ushort* __restrict__ g,
                                                 const uint* __restrict__ row_ptr,
                                                 const int2* __restrict__ srcid,
                                                 const float* __restrict__ eattr,
                                                 const float* __restrict__ We,
                                                 int N) {
    constexpr int VR = C / GSIZE;        // 8
    constexpr int TH = 3 * C;
    constexpr int GPB = 256 / GSIZE;
    __shared__ float swex[GPB][17];      // +1 pad: conflict-free group reads
    const float scale = (C == 128) ? 0.08838834764831843f : 0.0625f;  // 1/sqrt(C)
    const float foldk = 16.0f / (float)GSIZE;  // attr replication compensation

    int lane = threadIdx.x & (GSIZE - 1);
    int grp = threadIdx.x / GSIZE;
    int f = lane & 15;
    int node = blockIdx.x * GPB + grp;
    if (node >= N) return;
    int lvr = lane * VR;

    // q packed as 4x half2 (feeds fdot2 directly; no unpack)
    uint4 qv = *(const uint4*)(H + (size_t)node * TH + lvr);
    h16x2 q0 = bch2(qv.x), q1 = bch2(qv.y), q2 = bch2(qv.z), q3 = bch2(qv.w);
    float fg = foldk * h2f(g[(size_t)node * 16 + f]);
    uint beg = row_ptr[node], end = row_ptr[node + 1];

    float l = 0.f, w = 0.f;
    f32x2 acc[4];
#pragma unroll
    for (int j = 0; j < 4; ++j) acc[j] = (f32x2){0.f, 0.f};

    for (uint t = beg; t < end; t += 2) {
        uint t1 = (t + 1 < end) ? t + 1 : t;   // replicate-last; masked by e=0
        int2 se0 = srcid[t], se1 = srcid[t1];
        float at0 = eattr[(size_t)se0.y * 16 + f];
        float at1 = eattr[(size_t)se1.y * 16 + f];
        const ushort* hb0 = H + (size_t)se0.x * TH + C + lvr;
        const ushort* hb1 = H + (size_t)se1.x * TH + C + lvr;
        uint4 k0 = *(const uint4*)hb0, v0 = *(const uint4*)(hb0 + C);
        uint4 k1 = *(const uint4*)hb1, v1 = *(const uint4*)(hb1 + C);

        float p0 = at0 * fg, p1 = at1 * fg;
        p0 = FDOT2(q0, bch2(k0.x), p0); p0 = FDOT2(q1, bch2(k0.y), p0);
        p0 = FDOT2(q2, bch2(k0.z), p0); p0 = FDOT2(q3, bch2(k0.w), p0);
        p1 = FDOT2(q0, bch2(k1.x), p1); p1 = FDOT2(q1, bch2(k1.y), p1);
        p1 = FDOT2(q2, bch2(k1.z), p1); p1 = FDOT2(q3, bch2(k1.w), p1);

        p0 += __shfl_xor(p0, 1); p1 += __shfl_xor(p1, 1);
        p0 += __shfl_xor(p0, 2); p1 += __shfl_xor(p1, 2);
        p0 += __shfl_xor(p0, 4); p1 += __shfl_xor(p1, 4);
        p0 += __shfl_xor(p0, 8); p1 += __shfl_xor(p1, 8);
        if (GSIZE == 32) {
            p0 += __shfl_xor(p0, 16); p1 += __shfl_xor(p1, 16);
        }
        float e0 = __expf(p0 * scale);
        float e1 = (t + 1 < end) ? __expf(p1 * scale) : 0.f;
        l += e0 + e1;
        w = fmaf(e0, at0, w);
        w = fmaf(e1, at1, w);
        f32x2 eb;
        eb = (f32x2){e0, e0};
        acc[0] = __builtin_elementwise_fma(cvt2(v0.x), eb, acc[0]);
        acc[1] = __builtin_elementwise_fma(cvt2(v0.y), eb, acc[1]);
        acc[2] = __builtin_elementwise_fma(cvt2(v0.z), eb, acc[2]);
        acc[3] = __builtin_elementwise_fma(cvt2(v0.w), eb, acc[3]);
        eb = (f32x2){e1, e1};
        acc[0] = __builtin_elementwise_fma(cvt2(v1.x), eb, acc[0]);
        acc[1] = __builtin_elementwise_fma(cvt2(v1.y), eb, acc[1]);
        acc[2] = __builtin_elementwise_fma(cvt2(v1.z), eb, acc[2]);
        acc[3] = __builtin_elementwise_fma(cvt2(v1.w), eb, acc[3]);
    }

    float inv = 1.f / (l + 1e-16f);   // empty node: acc=w=0 -> out = skip
    // exchange w_f (held on lane f; duplicated on lane 16+f when GSIZE=32)
    if (lane < 16) swex[grp][lane] = w;
    // same-wave LDS RAW: compiler inserts lgkmcnt wait; no barrier needed
    f32x2 ew[4];
#pragma unroll
    for (int j = 0; j < 4; ++j) ew[j] = (f32x2){0.f, 0.f};
#pragma unroll
    for (int f2i = 0; f2i < 16; ++f2i) {
        float wfs = swex[grp][f2i];
        f32x2 wf = (f32x2){wfs, wfs};
        const f32x4* wrow = (const f32x4*)(We + f2i * C + lvr);
        f32x4 c0 = wrow[0], c1 = wrow[1];
        ew[0] = __builtin_elementwise_fma(c0.lo, wf, ew[0]);
        ew[1] = __builtin_elementwise_fma(c0.hi, wf, ew[1]);
        ew[2] = __builtin_elementwise_fma(c1.lo, wf, ew[2]);
        ew[3] = __builtin_elementwise_fma(c1.hi, wf, ew[3]);
    }
    ushort* srow = S + (size_t)node * C + lvr;
    uint4 skv = *(const uint4*)srow;
    const uint* sp = (const uint*)&skv;
    uint4 ov;
    uint* op = (uint*)&ov;
#pragma unroll
    for (int hh = 0; hh < 4; ++hh) {
        f32x2 sk = cvt2(sp[hh]);
        float o0 = (acc[hh].x + ew[hh].x) * inv + sk.x;
        float o1 = (acc[hh].y + ew[hh].y) * inv + sk.y;
        if (RELU) { o0 = fmaxf(o0, 0.f); o1 = fmaxf(o1, 0.f); }
        op[hh] = (uint)f2h(o0) | ((uint)f2h(o1) << 16);
    }
    *(uint4*)srow = ov;
}

// ---------------- classifier: out[N,10] = h3(f16) @ Wc + bc ----------------
__global__ void k_cls(const ushort* __restrict__ h, const float* __restrict__ Wc,
                      const float* __restrict__ bc, float* __restrict__ outp, int N) {
    int t = blockIdx.x * 256 + threadIdx.x;
    int node = t >> 4;
    int c = t & 15;
    if (node >= N || c >= 10) return;
    const ushort* hr = h + (size_t)node * 256;
    float acc = 0.f;
#pragma unroll 4
    for (int k4 = 0; k4 < 64; ++k4) {
        uint2 u = *(const uint2*)(hr + k4 * 4);
        f32x2 a01 = cvt2(u.x);
        f32x2 a23 = cvt2(u.y);
        int kb = k4 * 4;
        acc = fmaf(a01.x, Wc[(kb + 0) * 10 + c], acc);
        acc = fmaf(a01.y, Wc[(kb + 1) * 10 + c], acc);
        acc = fmaf(a23.x, Wc[(kb + 2) * 10 + c], acc);
        acc = fmaf(a23.y, Wc[(kb + 3) * 10 + c], acc);
    }
    outp[node * 10 + c] = acc + bc[c];
}

// ---------------- launch ----------------
extern "C" void kernel_launch(void* const* d_in, const int* in_sizes, int n_in,
                              void* d_out, int out_size, void* d_ws, size_t ws_size,
                              hipStream_t stream) {
    const float* x = (const float*)d_in[0];
    const int* ei = (const int*)d_in[1];
    const float* eattr = (const float*)d_in[2];
    const int N = in_sizes[0] / 128;
    const int E = in_sizes[1] / 2;

    const float* Wq[3], *bq[3], *Wk[3], *bk[3], *Wv[3], *bv[3], *We[3], *Ws[3], *bs[3];
    for (int li = 0; li < 3; ++li) {
        int base = 3 + li * 9;
        Wq[li] = (const float*)d_in[base + 0];
        bq[li] = (const float*)d_in[base + 1];
        Wk[li] = (const float*)d_in[base + 2];
        bk[li] = (const float*)d_in[base + 3];
        Wv[li] = (const float*)d_in[base + 4];
        bv[li] = (const float*)d_in[base + 5];
        We[li] = (const float*)d_in[base + 6];
        Ws[li] = (const float*)d_in[base + 7];
        bs[li] = (const float*)d_in[base + 8];
    }
    const float* Wc = (const float*)d_in[30];
    const float* bc = (const float*)d_in[31];

    // workspace carve (~243 MB -- R12 budget)
    size_t off = 0;
    char* base = (char*)d_ws;
    auto alloc = [&](size_t bytes) -> void* {
        void* p = base + off;
        off = (off + bytes + 255) & ~(size_t)255;
        return p;
    };
    ushort* SA = (ushort*)alloc((size_t)N * 256 * 2);   // skip/out ping
    ushort* SB = (ushort*)alloc((size_t)N * 128 * 2);   // pong (also xb)
    ushort* H  = (ushort*)alloc((size_t)N * 768 * 2);   // q|k|v (max 3C)
    ushort* gbuf = (ushort*)alloc((size_t)N * 16 * 2);  // g = We.q per node
    ushort* Bp = (ushort*)alloc(140000 * 2);            // packed weights
    float* biasc = (float*)alloc(1040 * 4);
    float* Wgf = (float*)alloc(2048 * 4);
    float* bgf = (float*)alloc(16 * 4);
    uint* row_ptr = (uint*)alloc((size_t)(N + 1) * 4);
    uint* counts = (uint*)alloc((size_t)N * 4);
    uint* cursor = (uint*)alloc((size_t)N * 4);
    uint* bsum = (uint*)alloc(1024 * 4);
    int2* srcid = (int2*)alloc((size_t)E * 8);          // CSR {src, eidx}

    ushort* xb = SB;   // alias: xb dead after layer-1 GEMM

    int nb = (N + 1023) / 1024;

    // CSR build
    k_zero<<<(N + 255) / 256, 256, 0, stream>>>(counts, N);
    k_zero<<<(N + 255) / 256, 256, 0, stream>>>(cursor, N);
    k_hist<<<(E + 255) / 256, 256, 0, stream>>>(ei + E, counts, E, N);
    k_scan1<<<nb, 256, 0, stream>>>(counts, bsum, N);
    k_scan2<<<1, 64, 0, stream>>>(bsum, nb);
    k_scan3<<<nb, 256, 0, stream>>>(counts, bsum, row_ptr, N, E);
    k_fill<<<(E + 255) / 256, 256, 0, stream>>>(ei, row_ptr, cursor, srcid, E, N);

    // x -> f16
    int n4 = N * 128 / 4;
    k_cvt<<<(n4 + 255) / 256, 256, 0, stream>>>((const float4*)x, (ushort4*)xb, n4);

    int mt_total = N / 16;    // N divisible by 16
    for (int li = 0; li < 3; ++li) {
        int C = (li == 2) ? 256 : 128;
        int P = 4 * C + 16;
        int packTotal = 4 * (P >> 4) * 512;
        const ushort* A = (li == 0) ? xb : (li == 1) ? SA : SB;
        ushort* Sout = (li == 1) ? SB : SA;

        k_packg<<<9, 256, 0, stream>>>(Wq[li], bq[li], We[li], Wgf, bgf, C);
        k_packw<<<(packTotal + 255) / 256, 256, 0, stream>>>(Wq[li], Wk[li], Wv[li], Ws[li], Wgf, Bp, C);
        k_bias<<<(P + 255) / 256, 256, 0, stream>>>(bq[li], bk[li], bv[li], bs[li], bgf, biasc, C);
        k_gemm<<<dim3((P + 255) / 256, (mt_total + 7) / 8), 256, 0, stream>>>(A, Bp, biasc, H, Sout, gbuf, C, mt_total);
        if (li == 2)
            k_edge<256, 32, false><<<(N * 32 + 255) / 256, 256, 0, stream>>>(H, Sout, gbuf, row_ptr, srcid, eattr, We[li], N);
        else
            k_edge<128, 16, true><<<(N * 16 + 255) / 256, 256, 0, stream>>>(H, Sout, gbuf, row_ptr, srcid, eattr, We[li], N);
    }

    // classifier (layer-3 output is in SA)
    k_cls<<<(N * 16 + 255) / 256, 256, 0, stream>>>(SA, Wc, bc, (float*)d_out, N);
}